// Round 12
// baseline (1042.183 us; speedup 1.0000x reference)
//
#include <hip/hip_runtime.h>
#include <cstdint>
#include <cstddef>

using u16 = unsigned short;
using u32 = unsigned int;
typedef __attribute__((ext_vector_type(8))) short bf16x8;
typedef __attribute__((ext_vector_type(4))) float f32x4;

#define T_TOK 8192
#define SEQ   1024
#define NHEAD 16

__device__ __forceinline__ u16 f2b(float f) {
  u32 u = __float_as_uint(f);
  u32 r = (u + 0x7FFFu + ((u >> 16) & 1u)) >> 16;  // RNE
  return (u16)r;
}
__device__ __forceinline__ float b2f(u16 u) {
  return __uint_as_float(((u32)u) << 16);
}
// pack 2 f32 -> u32 holding {hi: bf16(b), lo: bf16(a)}, RNE (gfx950 HW cvt)
__device__ __forceinline__ u32 pk_bf16(float a, float b) {
  u32 r;
  asm("v_cvt_pk_bf16_f32 %0, %1, %2" : "=v"(r) : "v"(a), "v"(b));
  return r;
}

// ---------------- weight cast + transpose: fp32 [R][C] -> bf16 [C][R] ----------------
__global__ __launch_bounds__(256)
void k_cast_transpose(const float* __restrict__ in, u16* __restrict__ out, int R, int C) {
  __shared__ float tile[32][33];
  int bc = blockIdx.x * 32, br = blockIdx.y * 32;
  size_t bofs = (size_t)blockIdx.z * R * C;
  in += bofs; out += bofs;
  int tx = threadIdx.x, ty = threadIdx.y;  // 32 x 8
  for (int i = 0; i < 32; i += 8)
    tile[ty + i][tx] = in[(size_t)(br + ty + i) * C + bc + tx];
  __syncthreads();
  for (int i = 0; i < 32; i += 8)
    out[(size_t)(bc + ty + i) * R + br + tx] = f2b(tile[tx][ty + i]);
}

// ---------------- LayerNorm (fp32 in, bf16 out), one block per row of 1024 ----------------
__global__ __launch_bounds__(256)
void k_ln(const float* __restrict__ x, const float* __restrict__ g, const float* __restrict__ b,
          u16* __restrict__ out) {
  int row = blockIdx.x, t = threadIdx.x;
  float4 v = ((const float4*)(x + (size_t)row * 1024))[t];
  float s  = v.x + v.y + v.z + v.w;
  float ss = v.x * v.x + v.y * v.y + v.z * v.z + v.w * v.w;
  for (int d = 1; d < 64; d <<= 1) { s += __shfl_xor(s, d); ss += __shfl_xor(ss, d); }
  __shared__ float sm[8];
  int w = t >> 6, lane = t & 63;
  if (lane == 0) { sm[w] = s; sm[4 + w] = ss; }
  __syncthreads();
  s = sm[0] + sm[1] + sm[2] + sm[3];
  ss = sm[4] + sm[5] + sm[6] + sm[7];
  float mu = s * (1.f / 1024.f);
  float var = ss * (1.f / 1024.f) - mu * mu;
  float inv = rsqrtf(var + 1e-5f);
  float4 gv = ((const float4*)g)[t];
  float4 bv = ((const float4*)b)[t];
  u32 lo = pk_bf16((v.x - mu) * inv * gv.x + bv.x, (v.y - mu) * inv * gv.y + bv.y);
  u32 hi = pk_bf16((v.z - mu) * inv * gv.z + bv.z, (v.w - mu) * inv * gv.w + bv.w);
  u32* dst = (u32*)(out + (size_t)row * 1024 + t * 4);
  dst[0] = lo; dst[1] = hi;
}

// ---------------- GEMM: C[M,N] = A[M,K] @ BT[N,K]^T (+bias, epilogue modes) ----------------
// R10 structure (best measured): BK=32, global_load_lds linear dest + source-side XOR
// swizzle, double-buffered, one __syncthreads per K-step. R9 (counted-vmcnt ring) and
// R11 (BK=64) both regressed — this structure is TLP-hidden; keep LDS at 32KB.
// Expert GEMMs: grid-stride loop over by (no dead blocks, imbalance-robust); B pointers
// hoisted (B-tile L2-resident across by iterations on the same CU).
// XCD remap: EXPERT: xcd==expert, by fastest. dense: whole by-rows per XCD (ny==64).
// MODE 0: bf16 out, +bias | 1: f32, +bias+residual | 2: bf16, +bias+gelu | 3: f32, +bias
template<int MODE, bool EXPERT, bool GATHER>
__global__ __launch_bounds__(256)
void k_gemm(const u16* __restrict__ A, const u16* __restrict__ BT,
            const float* __restrict__ bias, const float* __restrict__ res,
            void* __restrict__ Cout, int M, int N, int Kd, int ldA,
            const int* __restrict__ off, const int* __restrict__ rows) {
  int nx = gridDim.x, ny = gridDim.y;
  int rid = blockIdx.x + nx * (blockIdx.y + ny * blockIdx.z);
  int z, bx, by0, bystep;
  if (EXPERT) {
    z = rid & 7;                 // XCD == expert
    int inner = rid >> 3;
    by0 = inner % ny;            // by fastest within XCD
    bx = inner / ny;
    bystep = ny;
  } else {
    z = 0;
    int xcd = rid & 7;
    int inner = rid >> 3;
    bx = inner % nx;
    by0 = (inner / nx) * 8 + xcd; // whole by-rows per XCD, bijective (ny==64)
    bystep = 1 << 20;             // run exactly once
  }
  int m_base = 0, M_local = M;
  if (EXPERT) { m_base = off[z]; M_local = off[z + 1] - m_base; }
  if (EXPERT) { BT += (size_t)z * N * Kd; bias += (size_t)z * N; }

  // linear [128][32] u16 tiles, double-buffered (8 KB each, 32 KB total)
  __shared__ alignas(1024) u16 As[2][4096];
  __shared__ alignas(1024) u16 Bs[2][4096];

  int t = threadIdx.x;
  int lane = t & 63, w = t >> 6;
  int wm = w >> 1, wn = w & 1;
  int lr = lane & 15;
  int slot = lane >> 4;                         // logical k-slot (8 elems = 16B)
  int sx = (slot ^ ((lr >> 1) & 3)) << 3;       // swizzled element offset within row

  // staging geometry: wave w stages chunks {2w, 2w+1}; chunk = 16 rows x 64B.
  // lane l -> row chunk*16 + (l>>2); LDS linear (DMA = base + lane*16B);
  // source slot pre-swizzled so read-side XOR round-trips.
  int ssrc = (lane & 3) ^ ((lane >> 3) & 3);
  const u16* bG[2];
  int rlc[2], cofs[2];
#pragma unroll
  for (int c = 0; c < 2; c++) {
    int chunk = 2 * w + c;
    rlc[c] = chunk * 16 + (lane >> 2);          // 0..127
    bG[c] = BT + (size_t)(bx * 128 + rlc[c]) * Kd + ssrc * 8;
    cofs[c] = chunk * 512;
  }

  for (int by = by0; by * 128 < M_local; by += bystep) {
    const u16* aG[2];
#pragma unroll
    for (int c = 0; c < 2; c++) {
      int mr = by * 128 + rlc[c];
      int mc = mr < M_local - 1 ? mr : M_local - 1;
      size_t arow = GATHER ? (size_t)rows[m_base + mc] : (size_t)(m_base + mc);
      aG[c] = A + arow * (size_t)ldA + ssrc * 8;
    }

    auto stage = [&](int k0, int buf) {
#pragma unroll
      for (int c = 0; c < 2; c++) {
        __builtin_amdgcn_global_load_lds(
            (const __attribute__((address_space(1))) void*)(aG[c] + k0),
            (__attribute__((address_space(3))) void*)(&As[buf][cofs[c]]), 16, 0, 0);
        __builtin_amdgcn_global_load_lds(
            (const __attribute__((address_space(1))) void*)(bG[c] + k0),
            (__attribute__((address_space(3))) void*)(&Bs[buf][cofs[c]]), 16, 0, 0);
      }
    };

    f32x4 acc[4][4] = {};

    stage(0, 0);
    __syncthreads();                    // compiler drains vmcnt(0) before barrier
    int cur = 0;
    for (int k0 = 0; k0 < Kd; k0 += 32) {
      if (k0 + 32 < Kd) stage(k0 + 32, cur ^ 1);  // async prefetch into other buffer
      bf16x8 af[4], bfr[4];
#pragma unroll
      for (int m = 0; m < 4; m++)
        af[m] = *(const bf16x8*)&As[cur][(wm * 64 + m * 16 + lr) * 32 + sx];
#pragma unroll
      for (int n = 0; n < 4; n++)
        bfr[n] = *(const bf16x8*)&Bs[cur][(wn * 64 + n * 16 + lr) * 32 + sx];
#pragma unroll
      for (int m = 0; m < 4; m++)
#pragma unroll
        for (int n = 0; n < 4; n++)
          acc[m][n] = __builtin_amdgcn_mfma_f32_16x16x32_bf16(af[m], bfr[n], acc[m][n], 0, 0, 0);
      __syncthreads();                  // drains my prefetch (vmcnt) + everyone's ds_reads
      cur ^= 1;
    }

    int cr = (lane >> 4) * 4, cc = lane & 15;
#pragma unroll
    for (int m = 0; m < 4; m++) {
      int rl = by * 128 + wm * 64 + m * 16 + cr;   // M_local-relative row base
#pragma unroll
      for (int n = 0; n < 4; n++) {
        int col = bx * 128 + wn * 64 + n * 16 + cc;
        float bia = bias[col];
        float v0 = acc[m][n][0] + bia, v1 = acc[m][n][1] + bia;
        float v2 = acc[m][n][2] + bia, v3 = acc[m][n][3] + bia;
        if (MODE == 2) {
          // gelu(tanh approx): v/(1+exp2(c*u)), c = -2*log2(e)*0.7978845608
          const float cc2 = -2.3025850929940457f;
          float u0 = v0 + 0.044715f * v0 * v0 * v0;
          float u1 = v1 + 0.044715f * v1 * v1 * v1;
          float u2 = v2 + 0.044715f * v2 * v2 * v2;
          float u3 = v3 + 0.044715f * v3 * v3 * v3;
          v0 = v0 / (1.f + exp2f(cc2 * u0));
          v1 = v1 / (1.f + exp2f(cc2 * u1));
          v2 = v2 / (1.f + exp2f(cc2 * u2));
          v3 = v3 / (1.f + exp2f(cc2 * u3));
        }
        if (MODE == 0 || MODE == 2) {
          u32 p01 = pk_bf16(v0, v1), p23 = pk_bf16(v2, v3);
          u16* cp = (u16*)Cout;
          if (rl + 0 < M_local) cp[(size_t)(m_base + rl + 0) * N + col] = (u16)p01;
          if (rl + 1 < M_local) cp[(size_t)(m_base + rl + 1) * N + col] = (u16)(p01 >> 16);
          if (rl + 2 < M_local) cp[(size_t)(m_base + rl + 2) * N + col] = (u16)p23;
          if (rl + 3 < M_local) cp[(size_t)(m_base + rl + 3) * N + col] = (u16)(p23 >> 16);
        } else {
          float* cp = (float*)Cout;
          float vv[4] = {v0, v1, v2, v3};
#pragma unroll
          for (int r = 0; r < 4; r++) {
            int rr = rl + r;
            if (rr >= M_local) continue;
            size_t row = (size_t)(m_base + rr);
            if (MODE == 1) cp[row * N + col] = vv[r] + res[row * N + col];
            else           cp[row * N + col] = vv[r];
          }
        }
      }
    }
  }
}

// ---------------- flash attention: qkv bf16 [T,3072] -> ao bf16 [T,1024] ----------------
__global__ __launch_bounds__(256)
void k_attn(const u16* __restrict__ qkv, u16* __restrict__ ao) {
  __shared__ u16 Kt[64][72];       // [key][hd]
  __shared__ u16 Vt[64][72];       // [hd][key] (transposed at staging)
  __shared__ u16 Pl[4][16][72];    // per-wave P round-trip [qrow][key]

  int bh = blockIdx.y;
  int b = bh >> 4, h = bh & 15;
  int q0 = blockIdx.x * 64;
  int t = threadIdx.x, lane = t & 63, w = t >> 6;
  int lr = lane & 15, lk = (lane >> 4) * 8;

  int tq = b * SEQ + q0 + w * 16 + lr;
  const u16* qrow = qkv + (size_t)tq * 3072 + h * 64;
  bf16x8 qf[2];
#pragma unroll
  for (int kk = 0; kk < 2; kk++) {
    bf16x8 raw = *(const bf16x8*)(qrow + kk * 32 + lk);
#pragma unroll
    for (int j = 0; j < 8; j++) raw[j] = (short)f2b(b2f((u16)raw[j]) * 0.125f);
    qf[kk] = raw;
  }

  float m[4], l[4];
  f32x4 o[4];
#pragma unroll
  for (int r = 0; r < 4; r++) { m[r] = -1e30f; l[r] = 0.f; }
#pragma unroll
  for (int c = 0; c < 4; c++) o[c] = (f32x4){0.f, 0.f, 0.f, 0.f};

  int key_r = t >> 2;         // 0..63
  int key_c = (t & 3) * 16;   // 0,16,32,48

  for (int kv0 = 0; kv0 < SEQ; kv0 += 64) {
    int tk = b * SEQ + kv0 + key_r;
    const u16* krow = qkv + (size_t)tk * 3072 + 1024 + h * 64 + key_c;
    const u16* vrow = qkv + (size_t)tk * 3072 + 2048 + h * 64 + key_c;
    int4 ka = *(const int4*)krow;
    int4 kb = *(const int4*)(krow + 8);
    int4 vv4[2];
    vv4[0] = *(const int4*)vrow;
    vv4[1] = *(const int4*)(vrow + 8);
    const u16* vv = (const u16*)vv4;
    __syncthreads();
    *(int4*)&Kt[key_r][key_c] = ka;
    *(int4*)&Kt[key_r][key_c + 8] = kb;
#pragma unroll
    for (int j = 0; j < 16; j++) Vt[key_c + j][key_r] = vv[j];
    __syncthreads();

    f32x4 s[4];
#pragma unroll
    for (int n = 0; n < 4; n++) {
      s[n] = (f32x4){0.f, 0.f, 0.f, 0.f};
#pragma unroll
      for (int kk = 0; kk < 2; kk++) {
        bf16x8 kf = *(const bf16x8*)&Kt[n * 16 + lr][kk * 32 + lk];
        s[n] = __builtin_amdgcn_mfma_f32_16x16x32_bf16(qf[kk], kf, s[n], 0, 0, 0);
      }
    }
    float alpha[4], rsum[4];
#pragma unroll
    for (int r = 0; r < 4; r++) {
      float mx = fmaxf(fmaxf(s[0][r], s[1][r]), fmaxf(s[2][r], s[3][r]));
#pragma unroll
      for (int d = 1; d < 16; d <<= 1) mx = fmaxf(mx, __shfl_xor(mx, d));
      float mn = fmaxf(m[r], mx);
      alpha[r] = expf(m[r] - mn);
      m[r] = mn;
      rsum[r] = 0.f;
    }
#pragma unroll
    for (int n = 0; n < 4; n++)
#pragma unroll
      for (int r = 0; r < 4; r++) {
        float p = expf(s[n][r] - m[r]);
        rsum[r] += p;
        Pl[w][(lane >> 4) * 4 + r][n * 16 + lr] = f2b(p);
      }
#pragma unroll
    for (int r = 0; r < 4; r++) {
      float rs = rsum[r];
#pragma unroll
      for (int d = 1; d < 16; d <<= 1) rs += __shfl_xor(rs, d);
      l[r] = l[r] * alpha[r] + rs;
#pragma unroll
      for (int c = 0; c < 4; c++) o[c][r] *= alpha[r];
    }
    bf16x8 pa[2];
#pragma unroll
    for (int kk = 0; kk < 2; kk++) pa[kk] = *(const bf16x8*)&Pl[w][lr][kk * 32 + lk];
#pragma unroll
    for (int c = 0; c < 4; c++)
#pragma unroll
      for (int kk = 0; kk < 2; kk++) {
        bf16x8 vf = *(const bf16x8*)&Vt[c * 16 + lr][kk * 32 + lk];
        o[c] = __builtin_amdgcn_mfma_f32_16x16x32_bf16(pa[kk], vf, o[c], 0, 0, 0);
      }
  }

  int cr = (lane >> 4) * 4, cc = lane & 15;
#pragma unroll
  for (int r = 0; r < 4; r++) {
    float invl = 1.f / l[r];
    int trow = b * SEQ + q0 + w * 16 + cr + r;
#pragma unroll
    for (int c = 0; c < 4; c++)
      ao[(size_t)trow * 1024 + h * 64 + c * 16 + cc] = f2b(o[c][r] * invl);
  }
}

// ---------------- router + LN2: fp32 LN for logits, emits bf16 n2b, per-block partials ----
// grid: 256 blocks x 256 threads; block handles 32 rows (4 waves x 8 rows).
__global__ __launch_bounds__(256)
void k_router(const float* __restrict__ x1, const float* __restrict__ g, const float* __restrict__ b,
              const float* __restrict__ Wr, u16* __restrict__ n2b,
              int* __restrict__ topi, float* __restrict__ topv,
              int* __restrict__ cnt_part, float* __restrict__ sp_part) {
  __shared__ int lcnt[8];
  __shared__ float lsp[8];
  int t = threadIdx.x, w = t >> 6, lane = t & 63;
  if (t < 8) { lcnt[t] = 0; lsp[t] = 0.f; }
  __syncthreads();

  float gv[16], bv[16];
#pragma unroll
  for (int i = 0; i < 4; i++) {
    float4 g4 = ((const float4*)g)[lane * 4 + i];
    float4 b4 = ((const float4*)b)[lane * 4 + i];
    gv[i * 4 + 0] = g4.x; gv[i * 4 + 1] = g4.y; gv[i * 4 + 2] = g4.z; gv[i * 4 + 3] = g4.w;
    bv[i * 4 + 0] = b4.x; bv[i * 4 + 1] = b4.y; bv[i * 4 + 2] = b4.z; bv[i * 4 + 3] = b4.w;
  }
  float wr[16][8];
#pragma unroll
  for (int j = 0; j < 16; j++) {
    float4 w0 = ((const float4*)Wr)[(lane * 16 + j) * 2];
    float4 w1 = ((const float4*)Wr)[(lane * 16 + j) * 2 + 1];
    wr[j][0] = w0.x; wr[j][1] = w0.y; wr[j][2] = w0.z; wr[j][3] = w0.w;
    wr[j][4] = w1.x; wr[j][5] = w1.y; wr[j][6] = w1.z; wr[j][7] = w1.w;
  }

  for (int i = 0; i < 8; i++) {
    int row = blockIdx.x * 32 + w * 8 + i;
    const float4* xr = (const float4*)(x1 + (size_t)row * 1024);
    float xv[16];
    float s = 0.f, ss = 0.f;
#pragma unroll
    for (int q = 0; q < 4; q++) {
      float4 v = xr[lane * 4 + q];
      xv[q * 4 + 0] = v.x; xv[q * 4 + 1] = v.y; xv[q * 4 + 2] = v.z; xv[q * 4 + 3] = v.w;
      s += v.x + v.y + v.z + v.w;
      ss += v.x * v.x + v.y * v.y + v.z * v.z + v.w * v.w;
    }
#pragma unroll
    for (int d = 1; d < 64; d <<= 1) { s += __shfl_xor(s, d); ss += __shfl_xor(ss, d); }
    float mu = s * (1.f / 1024.f);
    float var = ss * (1.f / 1024.f) - mu * mu;
    float inv = rsqrtf(var + 1e-5f);
    float p[8] = {};
#pragma unroll
    for (int j = 0; j < 16; j++) {
      float n = (xv[j] - mu) * inv * gv[j] + bv[j];
      xv[j] = n;                        // reuse as LN output
#pragma unroll
      for (int e = 0; e < 8; e++) p[e] += n * wr[j][e];
    }
    // emit bf16 n2 row (lane covers cols 16*lane..16*lane+15): 2 x uint4 stores
    {
      u32 pk[8];
#pragma unroll
      for (int jj = 0; jj < 8; jj++) pk[jj] = pk_bf16(xv[2 * jj], xv[2 * jj + 1]);
      uint4* dst = (uint4*)(n2b + (size_t)row * 1024 + lane * 16);
      dst[0] = make_uint4(pk[0], pk[1], pk[2], pk[3]);
      dst[1] = make_uint4(pk[4], pk[5], pk[6], pk[7]);
    }
#pragma unroll
    for (int e = 0; e < 8; e++)
#pragma unroll
      for (int d = 1; d < 64; d <<= 1) p[e] += __shfl_xor(p[e], d);
    if (lane == 0) {
      float mx = p[0];
#pragma unroll
      for (int e = 1; e < 8; e++) mx = fmaxf(mx, p[e]);
      float ex[8], sum = 0.f;
#pragma unroll
      for (int e = 0; e < 8; e++) { ex[e] = expf(p[e] - mx); sum += ex[e]; }
      float pr[8];
#pragma unroll
      for (int e = 0; e < 8; e++) pr[e] = ex[e] / sum;
      int i0 = 0; float b0 = pr[0];
      for (int e = 1; e < 8; e++) if (pr[e] > b0) { b0 = pr[e]; i0 = e; }
      int i1 = -1; float b1 = -1.f;
      for (int e = 0; e < 8; e++) if (e != i0 && pr[e] > b1) { b1 = pr[e]; i1 = e; }
      float inv2 = 1.f / (b0 + b1);
      topi[row * 2] = i0; topi[row * 2 + 1] = i1;
      topv[row * 2] = b0 * inv2; topv[row * 2 + 1] = b1 * inv2;
      atomicAdd(&lcnt[i0], 1); atomicAdd(&lcnt[i1], 1);
#pragma unroll
      for (int e = 0; e < 8; e++) atomicAdd(&lsp[e], pr[e]);
    }
  }
  __syncthreads();
  if (t < 8) {
    cnt_part[blockIdx.x * 8 + t] = lcnt[t];
    sp_part[blockIdx.x * 8 + t] = lsp[t];
  }
}

// ---------------- reduce partials -> offsets, cursor, aux (64 threads, 1 block) -----------
__global__ void k_scan_aux(const int* __restrict__ cnt_part, const float* __restrict__ sp_part,
                           int* __restrict__ off, int* __restrict__ cursor, float* __restrict__ aux_out) {
  __shared__ int csum[8];
  __shared__ float ssum[8];
  int t = threadIdx.x;           // 64 threads: expert = t&7, chunk = t>>3
  int e = t & 7, ch = t >> 3;
  int c = 0; float s = 0.f;
  for (int i = ch * 32; i < ch * 32 + 32; i++) { c += cnt_part[i * 8 + e]; s += sp_part[i * 8 + e]; }
#pragma unroll
  for (int d = 8; d < 64; d <<= 1) { c += __shfl_xor(c, d); s += __shfl_xor(s, d); }
  if (t < 8) { csum[t] = c; ssum[t] = s; }
  __syncthreads();
  if (t == 0) {
    int o = 0;
    for (int q = 0; q < 8; q++) { off[q] = o; cursor[q] = o; o += csum[q]; }
    off[8] = o;
    float aux = 0.f;
    for (int q = 0; q < 8; q++)
      aux += ((float)csum[q] / (float)(T_TOK * 2)) * (ssum[q] / (float)T_TOK);
    aux_out[0] = 8.f * aux;
  }
}

// ---------------- scatter: per-block LDS histogram + one range-atomic per expert ----------
__global__ __launch_bounds__(256)
void k_scatter(const int* __restrict__ topi, int* __restrict__ cursor,
               int* __restrict__ rows, int* __restrict__ slot_of) {
  __shared__ int hist[8];
  __shared__ int base[8];
  int t = threadIdx.x;
  if (t < 8) hist[t] = 0;
  __syncthreads();
  int tok = blockIdx.x * 256 + t;
  int e0 = topi[tok * 2], e1 = topi[tok * 2 + 1];
  int r0 = atomicAdd(&hist[e0], 1);
  int r1 = atomicAdd(&hist[e1], 1);
  __syncthreads();
  if (t < 8) base[t] = atomicAdd(&cursor[t], hist[t]);
  __syncthreads();
  int p0 = base[e0] + r0, p1 = base[e1] + r1;
  rows[p0] = tok; rows[p1] = tok;
  slot_of[tok * 2] = p0; slot_of[tok * 2 + 1] = p1;
}

__global__ __launch_bounds__(256)
void k_combine(const float* __restrict__ x1, const float* __restrict__ out2,
               const int* __restrict__ slot_of, const float* __restrict__ topv,
               float* __restrict__ out) {
  int row = blockIdx.x, t = threadIdx.x;
  int s0 = slot_of[row * 2], s1 = slot_of[row * 2 + 1];
  float w0 = topv[row * 2], w1 = topv[row * 2 + 1];
  float4 a  = ((const float4*)(x1 + (size_t)row * 1024))[t];
  float4 e0 = ((const float4*)(out2 + (size_t)s0 * 1024))[t];
  float4 e1 = ((const float4*)(out2 + (size_t)s1 * 1024))[t];
  float4 r;
  r.x = a.x + w0 * e0.x + w1 * e1.x;
  r.y = a.y + w0 * e0.y + w1 * e1.y;
  r.z = a.z + w0 * e0.z + w1 * e1.z;
  r.w = a.w + w0 * e0.w + w1 * e1.w;
  ((float4*)(out + (size_t)row * 1024))[t] = r;
}

extern "C" void kernel_launch(void* const* d_in, const int* in_sizes, int n_in,
                              void* d_out, int out_size, void* d_ws, size_t ws_size,
                              hipStream_t stream) {
  const float* x    = (const float*)d_in[0];
  const float* ln1g = (const float*)d_in[1];
  const float* ln1b = (const float*)d_in[2];
  const float* Wqkv = (const float*)d_in[3];
  const float* bqkv = (const float*)d_in[4];
  const float* Wo   = (const float*)d_in[5];
  const float* bo   = (const float*)d_in[6];
  const float* ln2g = (const float*)d_in[7];
  const float* ln2b = (const float*)d_in[8];
  const float* Wr   = (const float*)d_in[9];
  const float* W1   = (const float*)d_in[10];
  const float* b1   = (const float*)d_in[11];
  const float* W2   = (const float*)d_in[12];
  const float* b2   = (const float*)d_in[13];
  float* out = (float*)d_out;

  char* wp = (char*)d_ws;
  auto alloc = [&](size_t bytes) -> void* {
    void* p = (void*)wp;
    wp += (bytes + 255) & ~(size_t)255;
    return p;
  };
  u16*   WqkvT = (u16*)alloc((size_t)3072 * 1024 * 2);
  u16*   WoT   = (u16*)alloc((size_t)1024 * 1024 * 2);
  u16*   W1T   = (u16*)alloc((size_t)8 * 4096 * 1024 * 2);
  u16*   W2T   = (u16*)alloc((size_t)8 * 1024 * 4096 * 2);
  u16*   n1    = (u16*)alloc((size_t)8192 * 1024 * 2);
  u16*   qkv   = (u16*)alloc((size_t)8192 * 3072 * 2);
  u16*   aob   = (u16*)alloc((size_t)8192 * 1024 * 2);
  float* x1    = (float*)alloc((size_t)8192 * 1024 * 4);
  u16*   n2b   = (u16*)alloc((size_t)8192 * 1024 * 2);
  u16*   hbuf  = (u16*)alloc((size_t)16384 * 4096 * 2);
  float* out2  = (float*)alloc((size_t)16384 * 1024 * 4);
  int*   topi  = (int*)alloc((size_t)8192 * 2 * 4);
  float* topv  = (float*)alloc((size_t)8192 * 2 * 4);
  int*   rowsl = (int*)alloc((size_t)16384 * 4);
  int*   slot  = (int*)alloc((size_t)16384 * 4);
  int*   cntp  = (int*)alloc((size_t)256 * 8 * 4);
  float* spp   = (float*)alloc((size_t)256 * 8 * 4);
  int*   offs  = (int*)alloc(256);
  int*   curs  = (int*)alloc(256);

  k_cast_transpose<<<dim3(96, 32, 1), dim3(32, 8), 0, stream>>>(Wqkv, WqkvT, 1024, 3072);
  k_cast_transpose<<<dim3(32, 32, 1), dim3(32, 8), 0, stream>>>(Wo, WoT, 1024, 1024);
  k_cast_transpose<<<dim3(128, 32, 8), dim3(32, 8), 0, stream>>>(W1, W1T, 1024, 4096);
  k_cast_transpose<<<dim3(32, 128, 8), dim3(32, 8), 0, stream>>>(W2, W2T, 4096, 1024);

  k_ln<<<8192, 256, 0, stream>>>(x, ln1g, ln1b, n1);
  k_gemm<0, false, false><<<dim3(24, 64, 1), 256, 0, stream>>>(
      n1, WqkvT, bqkv, nullptr, qkv, 8192, 3072, 1024, 1024, nullptr, nullptr);
  k_attn<<<dim3(16, 128), 256, 0, stream>>>(qkv, aob);
  k_gemm<1, false, false><<<dim3(8, 64, 1), 256, 0, stream>>>(
      aob, WoT, bo, x, x1, 8192, 1024, 1024, 1024, nullptr, nullptr);

  k_router<<<256, 256, 0, stream>>>(x1, ln2g, ln2b, Wr, n2b, topi, topv, cntp, spp);
  k_scan_aux<<<1, 64, 0, stream>>>(cntp, spp, offs, curs, out + 8388608);
  k_scatter<<<32, 256, 0, stream>>>(topi, curs, rowsl, slot);

  k_gemm<2, true, true><<<dim3(32, 16, 8), 256, 0, stream>>>(
      n2b, W1T, b1, nullptr, hbuf, 0, 4096, 1024, 1024, offs, rowsl);
  k_gemm<3, true, false><<<dim3(8, 16, 8), 256, 0, stream>>>(
      hbuf, W2T, b2, nullptr, out2, 0, 1024, 4096, 4096, offs, nullptr);
  k_combine<<<8192, 256, 0, stream>>>(x1, out2, slot, topv, out);
}

// Round 13
// 882.014 us; speedup vs baseline: 1.1816x; 1.1816x over previous
//
#include <hip/hip_runtime.h>
#include <cstdint>
#include <cstddef>

using u16 = unsigned short;
using u32 = unsigned int;
typedef __attribute__((ext_vector_type(8))) short bf16x8;
typedef __attribute__((ext_vector_type(4))) float f32x4;

#define T_TOK 8192
#define SEQ   1024
#define NHEAD 16

__device__ __forceinline__ u16 f2b(float f) {
  u32 u = __float_as_uint(f);
  u32 r = (u + 0x7FFFu + ((u >> 16) & 1u)) >> 16;  // RNE
  return (u16)r;
}
__device__ __forceinline__ float b2f(u16 u) {
  return __uint_as_float(((u32)u) << 16);
}
// pack 2 f32 -> u32 holding {hi: bf16(b), lo: bf16(a)}, RNE (gfx950 HW cvt)
__device__ __forceinline__ u32 pk_bf16(float a, float b) {
  u32 r;
  asm("v_cvt_pk_bf16_f32 %0, %1, %2" : "=v"(r) : "v"(a), "v"(b));
  return r;
}

// ---------------- weight cast + transpose: fp32 [R][C] -> bf16 [C][R] ----------------
__global__ __launch_bounds__(256)
void k_cast_transpose(const float* __restrict__ in, u16* __restrict__ out, int R, int C) {
  __shared__ float tile[32][33];
  int bc = blockIdx.x * 32, br = blockIdx.y * 32;
  size_t bofs = (size_t)blockIdx.z * R * C;
  in += bofs; out += bofs;
  int tx = threadIdx.x, ty = threadIdx.y;  // 32 x 8
  for (int i = 0; i < 32; i += 8)
    tile[ty + i][tx] = in[(size_t)(br + ty + i) * C + bc + tx];
  __syncthreads();
  for (int i = 0; i < 32; i += 8)
    out[(size_t)(bc + ty + i) * R + br + tx] = f2b(tile[tx][ty + i]);
}

// ---------------- LayerNorm (fp32 in, bf16 out), one block per row of 1024 ----------------
__global__ __launch_bounds__(256)
void k_ln(const float* __restrict__ x, const float* __restrict__ g, const float* __restrict__ b,
          u16* __restrict__ out) {
  int row = blockIdx.x, t = threadIdx.x;
  float4 v = ((const float4*)(x + (size_t)row * 1024))[t];
  float s  = v.x + v.y + v.z + v.w;
  float ss = v.x * v.x + v.y * v.y + v.z * v.z + v.w * v.w;
  for (int d = 1; d < 64; d <<= 1) { s += __shfl_xor(s, d); ss += __shfl_xor(ss, d); }
  __shared__ float sm[8];
  int w = t >> 6, lane = t & 63;
  if (lane == 0) { sm[w] = s; sm[4 + w] = ss; }
  __syncthreads();
  s = sm[0] + sm[1] + sm[2] + sm[3];
  ss = sm[4] + sm[5] + sm[6] + sm[7];
  float mu = s * (1.f / 1024.f);
  float var = ss * (1.f / 1024.f) - mu * mu;
  float inv = rsqrtf(var + 1e-5f);
  float4 gv = ((const float4*)g)[t];
  float4 bv = ((const float4*)b)[t];
  u32 lo = pk_bf16((v.x - mu) * inv * gv.x + bv.x, (v.y - mu) * inv * gv.y + bv.y);
  u32 hi = pk_bf16((v.z - mu) * inv * gv.z + bv.z, (v.w - mu) * inv * gv.w + bv.w);
  u32* dst = (u32*)(out + (size_t)row * 1024 + t * 4);
  dst[0] = lo; dst[1] = hi;
}

// ---------------- GEMM: C[M,N] = A[M,K] @ BT[N,K]^T (+bias, epilogue modes) ----------------
// R10 structure VERBATIM (best measured, 905us): BK=32, global_load_lds linear dest +
// source-side XOR swizzle, double-buffered, one __syncthreads per K-step, fixed
// block->tile map with early-exit dead blocks. R9 (vmcnt ring), R11 (BK=64),
// R12 (grid-stride) all regressed — do not restructure this loop.
// XCD remap: EXPERT: xcd==expert, by fastest. dense: whole by-rows per XCD (ny==64).
// MODE 0: bf16 out, +bias | 1: f32, +bias+residual | 2: bf16, +bias+gelu | 3: f32, +bias
template<int MODE, bool EXPERT, bool GATHER>
__global__ __launch_bounds__(256)
void k_gemm(const u16* __restrict__ A, const u16* __restrict__ BT,
            const float* __restrict__ bias, const float* __restrict__ res,
            void* __restrict__ Cout, int M, int N, int Kd, int ldA,
            const int* __restrict__ off, const int* __restrict__ rows) {
  int nx = gridDim.x, ny = gridDim.y;
  int rid = blockIdx.x + nx * (blockIdx.y + ny * blockIdx.z);
  int z, bx, by;
  if (EXPERT) {
    z = rid & 7;                 // XCD == expert
    int inner = rid >> 3;
    by = inner % ny;             // by fastest: B-tile fixed, A-panel (L2-resident) sweeps
    bx = inner / ny;
  } else {
    z = 0;
    int xcd = rid & 7;
    int inner = rid >> 3;
    bx = inner % nx;
    by = (inner / nx) * 8 + xcd; // whole by-rows per XCD, bijective (ny==64)
  }
  int m_base = 0, M_local = M;
  if (EXPERT) { m_base = off[z]; M_local = off[z + 1] - m_base; }
  if (by * 128 >= M_local) return;
  if (EXPERT) { BT += (size_t)z * N * Kd; bias += (size_t)z * N; }

  // linear [128][32] u16 tiles, double-buffered (8 KB each, 32 KB total)
  __shared__ alignas(1024) u16 As[2][4096];
  __shared__ alignas(1024) u16 Bs[2][4096];

  int t = threadIdx.x;
  int lane = t & 63, w = t >> 6;
  int wm = w >> 1, wn = w & 1;
  int lr = lane & 15;
  int slot = lane >> 4;                         // logical k-slot (8 elems = 16B)
  int sx = (slot ^ ((lr >> 1) & 3)) << 3;       // swizzled element offset within row

  // staging geometry: wave w stages chunks {2w, 2w+1}; chunk = 16 rows x 64B.
  // lane l -> row chunk*16 + (l>>2); LDS linear (DMA = base + lane*16B);
  // source slot pre-swizzled so read-side XOR round-trips.
  int ssrc = (lane & 3) ^ ((lane >> 3) & 3);
  const u16* aG[2]; const u16* bG[2];
  u16* aL[2]; u16* bL[2];
#pragma unroll
  for (int c = 0; c < 2; c++) {
    int chunk = 2 * w + c;
    int rl = chunk * 16 + (lane >> 2);          // 0..127
    int mr = by * 128 + rl;
    int mc = mr < M_local - 1 ? mr : M_local - 1;
    size_t arow = GATHER ? (size_t)rows[m_base + mc] : (size_t)(m_base + mc);
    aG[c] = A + arow * (size_t)ldA + ssrc * 8;
    bG[c] = BT + (size_t)(bx * 128 + rl) * Kd + ssrc * 8;
    aL[c] = &As[0][chunk * 512];
    bL[c] = &Bs[0][chunk * 512];
  }

  auto stage = [&](int k0, int buf) {
#pragma unroll
    for (int c = 0; c < 2; c++) {
      __builtin_amdgcn_global_load_lds(
          (const __attribute__((address_space(1))) void*)(aG[c] + k0),
          (__attribute__((address_space(3))) void*)(aL[c] + buf * 4096), 16, 0, 0);
      __builtin_amdgcn_global_load_lds(
          (const __attribute__((address_space(1))) void*)(bG[c] + k0),
          (__attribute__((address_space(3))) void*)(bL[c] + buf * 4096), 16, 0, 0);
    }
  };

  f32x4 acc[4][4] = {};

  stage(0, 0);
  __syncthreads();                      // compiler drains vmcnt(0) before barrier
  int cur = 0;
  for (int k0 = 0; k0 < Kd; k0 += 32) {
    if (k0 + 32 < Kd) stage(k0 + 32, cur ^ 1);  // async prefetch into other buffer
    bf16x8 af[4], bfr[4];
#pragma unroll
    for (int m = 0; m < 4; m++)
      af[m] = *(const bf16x8*)&As[cur][(wm * 64 + m * 16 + lr) * 32 + sx];
#pragma unroll
    for (int n = 0; n < 4; n++)
      bfr[n] = *(const bf16x8*)&Bs[cur][(wn * 64 + n * 16 + lr) * 32 + sx];
#pragma unroll
    for (int m = 0; m < 4; m++)
#pragma unroll
      for (int n = 0; n < 4; n++)
        acc[m][n] = __builtin_amdgcn_mfma_f32_16x16x32_bf16(af[m], bfr[n], acc[m][n], 0, 0, 0);
    __syncthreads();                    // drains my prefetch (vmcnt) + everyone's ds_reads
    cur ^= 1;
  }

  int cr = (lane >> 4) * 4, cc = lane & 15;
#pragma unroll
  for (int m = 0; m < 4; m++) {
    int rl = by * 128 + wm * 64 + m * 16 + cr;   // M_local-relative row base
#pragma unroll
    for (int n = 0; n < 4; n++) {
      int col = bx * 128 + wn * 64 + n * 16 + cc;
      float bia = bias[col];
      float v0 = acc[m][n][0] + bia, v1 = acc[m][n][1] + bia;
      float v2 = acc[m][n][2] + bia, v3 = acc[m][n][3] + bia;
      if (MODE == 2) {
        // gelu(tanh approx): v/(1+exp2(c*u)), c = -2*log2(e)*0.7978845608
        const float cc2 = -2.3025850929940457f;
        float u0 = v0 + 0.044715f * v0 * v0 * v0;
        float u1 = v1 + 0.044715f * v1 * v1 * v1;
        float u2 = v2 + 0.044715f * v2 * v2 * v2;
        float u3 = v3 + 0.044715f * v3 * v3 * v3;
        v0 = v0 / (1.f + exp2f(cc2 * u0));
        v1 = v1 / (1.f + exp2f(cc2 * u1));
        v2 = v2 / (1.f + exp2f(cc2 * u2));
        v3 = v3 / (1.f + exp2f(cc2 * u3));
      }
      if (MODE == 0 || MODE == 2) {
        u32 p01 = pk_bf16(v0, v1), p23 = pk_bf16(v2, v3);
        u16* cp = (u16*)Cout;
        if (rl + 0 < M_local) cp[(size_t)(m_base + rl + 0) * N + col] = (u16)p01;
        if (rl + 1 < M_local) cp[(size_t)(m_base + rl + 1) * N + col] = (u16)(p01 >> 16);
        if (rl + 2 < M_local) cp[(size_t)(m_base + rl + 2) * N + col] = (u16)p23;
        if (rl + 3 < M_local) cp[(size_t)(m_base + rl + 3) * N + col] = (u16)(p23 >> 16);
      } else {
        float* cp = (float*)Cout;
        float vv[4] = {v0, v1, v2, v3};
#pragma unroll
        for (int r = 0; r < 4; r++) {
          int rr = rl + r;
          if (rr >= M_local) continue;
          size_t row = (size_t)(m_base + rr);
          if (MODE == 1) cp[row * N + col] = vv[r] + res[row * N + col];
          else           cp[row * N + col] = vv[r];
        }
      }
    }
  }
}

// ---------------- flash attention: qkv bf16 [T,3072] -> ao bf16 [T,1024] ----------------
__global__ __launch_bounds__(256)
void k_attn(const u16* __restrict__ qkv, u16* __restrict__ ao) {
  __shared__ u16 Kt[64][72];       // [key][hd]
  __shared__ u16 Vt[64][72];       // [hd][key] (transposed at staging)
  __shared__ u16 Pl[4][16][72];    // per-wave P round-trip [qrow][key]

  int bh = blockIdx.y;
  int b = bh >> 4, h = bh & 15;
  int q0 = blockIdx.x * 64;
  int t = threadIdx.x, lane = t & 63, w = t >> 6;
  int lr = lane & 15, lk = (lane >> 4) * 8;

  int tq = b * SEQ + q0 + w * 16 + lr;
  const u16* qrow = qkv + (size_t)tq * 3072 + h * 64;
  bf16x8 qf[2];
#pragma unroll
  for (int kk = 0; kk < 2; kk++) {
    bf16x8 raw = *(const bf16x8*)(qrow + kk * 32 + lk);
#pragma unroll
    for (int j = 0; j < 8; j++) raw[j] = (short)f2b(b2f((u16)raw[j]) * 0.125f);
    qf[kk] = raw;
  }

  float m[4], l[4];
  f32x4 o[4];
#pragma unroll
  for (int r = 0; r < 4; r++) { m[r] = -1e30f; l[r] = 0.f; }
#pragma unroll
  for (int c = 0; c < 4; c++) o[c] = (f32x4){0.f, 0.f, 0.f, 0.f};

  int key_r = t >> 2;         // 0..63
  int key_c = (t & 3) * 16;   // 0,16,32,48

  for (int kv0 = 0; kv0 < SEQ; kv0 += 64) {
    int tk = b * SEQ + kv0 + key_r;
    const u16* krow = qkv + (size_t)tk * 3072 + 1024 + h * 64 + key_c;
    const u16* vrow = qkv + (size_t)tk * 3072 + 2048 + h * 64 + key_c;
    int4 ka = *(const int4*)krow;
    int4 kb = *(const int4*)(krow + 8);
    int4 vv4[2];
    vv4[0] = *(const int4*)vrow;
    vv4[1] = *(const int4*)(vrow + 8);
    const u16* vv = (const u16*)vv4;
    __syncthreads();
    *(int4*)&Kt[key_r][key_c] = ka;
    *(int4*)&Kt[key_r][key_c + 8] = kb;
#pragma unroll
    for (int j = 0; j < 16; j++) Vt[key_c + j][key_r] = vv[j];
    __syncthreads();

    f32x4 s[4];
#pragma unroll
    for (int n = 0; n < 4; n++) {
      s[n] = (f32x4){0.f, 0.f, 0.f, 0.f};
#pragma unroll
      for (int kk = 0; kk < 2; kk++) {
        bf16x8 kf = *(const bf16x8*)&Kt[n * 16 + lr][kk * 32 + lk];
        s[n] = __builtin_amdgcn_mfma_f32_16x16x32_bf16(qf[kk], kf, s[n], 0, 0, 0);
      }
    }
    float alpha[4], rsum[4];
#pragma unroll
    for (int r = 0; r < 4; r++) {
      float mx = fmaxf(fmaxf(s[0][r], s[1][r]), fmaxf(s[2][r], s[3][r]));
#pragma unroll
      for (int d = 1; d < 16; d <<= 1) mx = fmaxf(mx, __shfl_xor(mx, d));
      float mn = fmaxf(m[r], mx);
      alpha[r] = expf(m[r] - mn);
      m[r] = mn;
      rsum[r] = 0.f;
    }
#pragma unroll
    for (int n = 0; n < 4; n++)
#pragma unroll
      for (int r = 0; r < 4; r++) {
        float p = expf(s[n][r] - m[r]);
        rsum[r] += p;
        Pl[w][(lane >> 4) * 4 + r][n * 16 + lr] = f2b(p);
      }
#pragma unroll
    for (int r = 0; r < 4; r++) {
      float rs = rsum[r];
#pragma unroll
      for (int d = 1; d < 16; d <<= 1) rs += __shfl_xor(rs, d);
      l[r] = l[r] * alpha[r] + rs;
#pragma unroll
      for (int c = 0; c < 4; c++) o[c][r] *= alpha[r];
    }
    bf16x8 pa[2];
#pragma unroll
    for (int kk = 0; kk < 2; kk++) pa[kk] = *(const bf16x8*)&Pl[w][lr][kk * 32 + lk];
#pragma unroll
    for (int c = 0; c < 4; c++)
#pragma unroll
      for (int kk = 0; kk < 2; kk++) {
        bf16x8 vf = *(const bf16x8*)&Vt[c * 16 + lr][kk * 32 + lk];
        o[c] = __builtin_amdgcn_mfma_f32_16x16x32_bf16(pa[kk], vf, o[c], 0, 0, 0);
      }
  }

  int cr = (lane >> 4) * 4, cc = lane & 15;
#pragma unroll
  for (int r = 0; r < 4; r++) {
    float invl = 1.f / l[r];
    int trow = b * SEQ + q0 + w * 16 + cr + r;
#pragma unroll
    for (int c = 0; c < 4; c++)
      ao[(size_t)trow * 1024 + h * 64 + c * 16 + cc] = f2b(o[c][r] * invl);
  }
}

// ---------------- router + LN2: fp32 LN for logits, emits bf16 n2b, per-block partials ----
// grid: 256 blocks x 256 threads; block handles 32 rows (4 waves x 8 rows).
__global__ __launch_bounds__(256)
void k_router(const float* __restrict__ x1, const float* __restrict__ g, const float* __restrict__ b,
              const float* __restrict__ Wr, u16* __restrict__ n2b,
              int* __restrict__ topi, float* __restrict__ topv,
              int* __restrict__ cnt_part, float* __restrict__ sp_part) {
  __shared__ int lcnt[8];
  __shared__ float lsp[8];
  int t = threadIdx.x, w = t >> 6, lane = t & 63;
  if (t < 8) { lcnt[t] = 0; lsp[t] = 0.f; }
  __syncthreads();

  float gv[16], bv[16];
#pragma unroll
  for (int i = 0; i < 4; i++) {
    float4 g4 = ((const float4*)g)[lane * 4 + i];
    float4 b4 = ((const float4*)b)[lane * 4 + i];
    gv[i * 4 + 0] = g4.x; gv[i * 4 + 1] = g4.y; gv[i * 4 + 2] = g4.z; gv[i * 4 + 3] = g4.w;
    bv[i * 4 + 0] = b4.x; bv[i * 4 + 1] = b4.y; bv[i * 4 + 2] = b4.z; bv[i * 4 + 3] = b4.w;
  }
  float wr[16][8];
#pragma unroll
  for (int j = 0; j < 16; j++) {
    float4 w0 = ((const float4*)Wr)[(lane * 16 + j) * 2];
    float4 w1 = ((const float4*)Wr)[(lane * 16 + j) * 2 + 1];
    wr[j][0] = w0.x; wr[j][1] = w0.y; wr[j][2] = w0.z; wr[j][3] = w0.w;
    wr[j][4] = w1.x; wr[j][5] = w1.y; wr[j][6] = w1.z; wr[j][7] = w1.w;
  }

  for (int i = 0; i < 8; i++) {
    int row = blockIdx.x * 32 + w * 8 + i;
    const float4* xr = (const float4*)(x1 + (size_t)row * 1024);
    float xv[16];
    float s = 0.f, ss = 0.f;
#pragma unroll
    for (int q = 0; q < 4; q++) {
      float4 v = xr[lane * 4 + q];
      xv[q * 4 + 0] = v.x; xv[q * 4 + 1] = v.y; xv[q * 4 + 2] = v.z; xv[q * 4 + 3] = v.w;
      s += v.x + v.y + v.z + v.w;
      ss += v.x * v.x + v.y * v.y + v.z * v.z + v.w * v.w;
    }
#pragma unroll
    for (int d = 1; d < 64; d <<= 1) { s += __shfl_xor(s, d); ss += __shfl_xor(ss, d); }
    float mu = s * (1.f / 1024.f);
    float var = ss * (1.f / 1024.f) - mu * mu;
    float inv = rsqrtf(var + 1e-5f);
    float p[8] = {};
#pragma unroll
    for (int j = 0; j < 16; j++) {
      float n = (xv[j] - mu) * inv * gv[j] + bv[j];
      xv[j] = n;                        // reuse as LN output
#pragma unroll
      for (int e = 0; e < 8; e++) p[e] += n * wr[j][e];
    }
    // emit bf16 n2 row (lane covers cols 16*lane..16*lane+15): 2 x uint4 stores
    {
      u32 pk[8];
#pragma unroll
      for (int jj = 0; jj < 8; jj++) pk[jj] = pk_bf16(xv[2 * jj], xv[2 * jj + 1]);
      uint4* dst = (uint4*)(n2b + (size_t)row * 1024 + lane * 16);
      dst[0] = make_uint4(pk[0], pk[1], pk[2], pk[3]);
      dst[1] = make_uint4(pk[4], pk[5], pk[6], pk[7]);
    }
#pragma unroll
    for (int e = 0; e < 8; e++)
#pragma unroll
      for (int d = 1; d < 64; d <<= 1) p[e] += __shfl_xor(p[e], d);
    if (lane == 0) {
      float mx = p[0];
#pragma unroll
      for (int e = 1; e < 8; e++) mx = fmaxf(mx, p[e]);
      float ex[8], sum = 0.f;
#pragma unroll
      for (int e = 0; e < 8; e++) { ex[e] = expf(p[e] - mx); sum += ex[e]; }
      float pr[8];
#pragma unroll
      for (int e = 0; e < 8; e++) pr[e] = ex[e] / sum;
      int i0 = 0; float b0 = pr[0];
      for (int e = 1; e < 8; e++) if (pr[e] > b0) { b0 = pr[e]; i0 = e; }
      int i1 = -1; float b1 = -1.f;
      for (int e = 0; e < 8; e++) if (e != i0 && pr[e] > b1) { b1 = pr[e]; i1 = e; }
      float inv2 = 1.f / (b0 + b1);
      topi[row * 2] = i0; topi[row * 2 + 1] = i1;
      topv[row * 2] = b0 * inv2; topv[row * 2 + 1] = b1 * inv2;
      atomicAdd(&lcnt[i0], 1); atomicAdd(&lcnt[i1], 1);
#pragma unroll
      for (int e = 0; e < 8; e++) atomicAdd(&lsp[e], pr[e]);
    }
  }
  __syncthreads();
  if (t < 8) {
    cnt_part[blockIdx.x * 8 + t] = lcnt[t];
    sp_part[blockIdx.x * 8 + t] = lsp[t];
  }
}

// ---------------- reduce partials -> offsets, cursor, aux (64 threads, 1 block) -----------
__global__ void k_scan_aux(const int* __restrict__ cnt_part, const float* __restrict__ sp_part,
                           int* __restrict__ off, int* __restrict__ cursor, float* __restrict__ aux_out) {
  __shared__ int csum[8];
  __shared__ float ssum[8];
  int t = threadIdx.x;           // 64 threads: expert = t&7, chunk = t>>3
  int e = t & 7, ch = t >> 3;
  int c = 0; float s = 0.f;
  for (int i = ch * 32; i < ch * 32 + 32; i++) { c += cnt_part[i * 8 + e]; s += sp_part[i * 8 + e]; }
#pragma unroll
  for (int d = 8; d < 64; d <<= 1) { c += __shfl_xor(c, d); s += __shfl_xor(s, d); }
  if (t < 8) { csum[t] = c; ssum[t] = s; }
  __syncthreads();
  if (t == 0) {
    int o = 0;
    for (int q = 0; q < 8; q++) { off[q] = o; cursor[q] = o; o += csum[q]; }
    off[8] = o;
    float aux = 0.f;
    for (int q = 0; q < 8; q++)
      aux += ((float)csum[q] / (float)(T_TOK * 2)) * (ssum[q] / (float)T_TOK);
    aux_out[0] = 8.f * aux;
  }
}

// ---------------- scatter: per-block LDS histogram + one range-atomic per expert ----------
__global__ __launch_bounds__(256)
void k_scatter(const int* __restrict__ topi, int* __restrict__ cursor,
               int* __restrict__ rows, int* __restrict__ slot_of) {
  __shared__ int hist[8];
  __shared__ int base[8];
  int t = threadIdx.x;
  if (t < 8) hist[t] = 0;
  __syncthreads();
  int tok = blockIdx.x * 256 + t;
  int e0 = topi[tok * 2], e1 = topi[tok * 2 + 1];
  int r0 = atomicAdd(&hist[e0], 1);
  int r1 = atomicAdd(&hist[e1], 1);
  __syncthreads();
  if (t < 8) base[t] = atomicAdd(&cursor[t], hist[t]);
  __syncthreads();
  int p0 = base[e0] + r0, p1 = base[e1] + r1;
  rows[p0] = tok; rows[p1] = tok;
  slot_of[tok * 2] = p0; slot_of[tok * 2 + 1] = p1;
}

// ---------------- combine: out = x1 + w0*out2[s0] + w1*out2[s1] (out2 is bf16) -----------
__global__ __launch_bounds__(256)
void k_combine(const float* __restrict__ x1, const u16* __restrict__ out2,
               const int* __restrict__ slot_of, const float* __restrict__ topv,
               float* __restrict__ out) {
  int row = blockIdx.x, t = threadIdx.x;
  int s0 = slot_of[row * 2], s1 = slot_of[row * 2 + 1];
  float w0 = topv[row * 2], w1 = topv[row * 2 + 1];
  float4 a = ((const float4*)(x1 + (size_t)row * 1024))[t];
  ushort4 e0 = ((const ushort4*)(out2 + (size_t)s0 * 1024))[t];
  ushort4 e1 = ((const ushort4*)(out2 + (size_t)s1 * 1024))[t];
  float4 r;
  r.x = a.x + w0 * b2f(e0.x) + w1 * b2f(e1.x);
  r.y = a.y + w0 * b2f(e0.y) + w1 * b2f(e1.y);
  r.z = a.z + w0 * b2f(e0.z) + w1 * b2f(e1.z);
  r.w = a.w + w0 * b2f(e0.w) + w1 * b2f(e1.w);
  ((float4*)(out + (size_t)row * 1024))[t] = r;
}

extern "C" void kernel_launch(void* const* d_in, const int* in_sizes, int n_in,
                              void* d_out, int out_size, void* d_ws, size_t ws_size,
                              hipStream_t stream) {
  const float* x    = (const float*)d_in[0];
  const float* ln1g = (const float*)d_in[1];
  const float* ln1b = (const float*)d_in[2];
  const float* Wqkv = (const float*)d_in[3];
  const float* bqkv = (const float*)d_in[4];
  const float* Wo   = (const float*)d_in[5];
  const float* bo   = (const float*)d_in[6];
  const float* ln2g = (const float*)d_in[7];
  const float* ln2b = (const float*)d_in[8];
  const float* Wr   = (const float*)d_in[9];
  const float* W1   = (const float*)d_in[10];
  const float* b1   = (const float*)d_in[11];
  const float* W2   = (const float*)d_in[12];
  const float* b2   = (const float*)d_in[13];
  float* out = (float*)d_out;

  char* wp = (char*)d_ws;
  auto alloc = [&](size_t bytes) -> void* {
    void* p = (void*)wp;
    wp += (bytes + 255) & ~(size_t)255;
    return p;
  };
  u16*   WqkvT = (u16*)alloc((size_t)3072 * 1024 * 2);
  u16*   WoT   = (u16*)alloc((size_t)1024 * 1024 * 2);
  u16*   W1T   = (u16*)alloc((size_t)8 * 4096 * 1024 * 2);
  u16*   W2T   = (u16*)alloc((size_t)8 * 1024 * 4096 * 2);
  u16*   n1    = (u16*)alloc((size_t)8192 * 1024 * 2);
  u16*   qkv   = (u16*)alloc((size_t)8192 * 3072 * 2);
  u16*   aob   = (u16*)alloc((size_t)8192 * 1024 * 2);
  float* x1    = (float*)alloc((size_t)8192 * 1024 * 4);
  u16*   n2b   = (u16*)alloc((size_t)8192 * 1024 * 2);
  u16*   hbuf  = (u16*)alloc((size_t)16384 * 4096 * 2);
  u16*   out2  = (u16*)alloc((size_t)16384 * 1024 * 2);
  int*   topi  = (int*)alloc((size_t)8192 * 2 * 4);
  float* topv  = (float*)alloc((size_t)8192 * 2 * 4);
  int*   rowsl = (int*)alloc((size_t)16384 * 4);
  int*   slot  = (int*)alloc((size_t)16384 * 4);
  int*   cntp  = (int*)alloc((size_t)256 * 8 * 4);
  float* spp   = (float*)alloc((size_t)256 * 8 * 4);
  int*   offs  = (int*)alloc(256);
  int*   curs  = (int*)alloc(256);

  k_cast_transpose<<<dim3(96, 32, 1), dim3(32, 8), 0, stream>>>(Wqkv, WqkvT, 1024, 3072);
  k_cast_transpose<<<dim3(32, 32, 1), dim3(32, 8), 0, stream>>>(Wo, WoT, 1024, 1024);
  k_cast_transpose<<<dim3(128, 32, 8), dim3(32, 8), 0, stream>>>(W1, W1T, 1024, 4096);
  k_cast_transpose<<<dim3(32, 128, 8), dim3(32, 8), 0, stream>>>(W2, W2T, 4096, 1024);

  k_ln<<<8192, 256, 0, stream>>>(x, ln1g, ln1b, n1);
  k_gemm<0, false, false><<<dim3(24, 64, 1), 256, 0, stream>>>(
      n1, WqkvT, bqkv, nullptr, qkv, 8192, 3072, 1024, 1024, nullptr, nullptr);
  k_attn<<<dim3(16, 128), 256, 0, stream>>>(qkv, aob);
  k_gemm<1, false, false><<<dim3(8, 64, 1), 256, 0, stream>>>(
      aob, WoT, bo, x, x1, 8192, 1024, 1024, 1024, nullptr, nullptr);

  k_router<<<256, 256, 0, stream>>>(x1, ln2g, ln2b, Wr, n2b, topi, topv, cntp, spp);
  k_scan_aux<<<1, 64, 0, stream>>>(cntp, spp, offs, curs, out + 8388608);
  k_scatter<<<32, 256, 0, stream>>>(topi, curs, rowsl, slot);

  k_gemm<2, true, true><<<dim3(32, 64, 8), 256, 0, stream>>>(
      n2b, W1T, b1, nullptr, hbuf, 0, 4096, 1024, 1024, offs, rowsl);
  k_gemm<0, true, false><<<dim3(8, 64, 8), 256, 0, stream>>>(
      hbuf, W2T, b2, nullptr, out2, 0, 1024, 4096, 4096, offs, nullptr);
  k_combine<<<8192, 256, 0, stream>>>(x1, out2, slot, topv, out);
}